// Round 13
// baseline (104.947 us; speedup 1.0000x reference)
//
#include <hip/hip_runtime.h>

// Conv2d 3x3, cin=4, cout=4, pad=1, stride=1 on [4,4096,4096] fp32.
//
// Round-13 = round-9 (97.9 us best) made WAVE-PRIVATE and BARRIER-FREE.
// Each wave owns a 256-px sub-strip: it DMA-stages its own 6 input rows
// (global_load_lds width=16) + its own 12 halo scalars (one width=4 DMA,
// lanes 0..11) into its own double-buffered LDS region. No cross-wave
// data flow => NO s_barrier anywhere; each wave self-syncs on its own
// counted s_waitcnt vmcnt(7) (stage ci+1 stays in flight across compute ci)
// and lgkmcnt(0) before re-staging a buffer (ds_read and DMA-write live in
// different wait queues). Removes the 4-wave lockstep convoy of R9.
// LDS 49.5 KB (unchanged, 3 blocks/CU); tile/stores identical to R9.

#define IW 4096
#define IH 4096
constexpr long long HWsz = (long long)IH * IW;

typedef float v4f __attribute__((ext_vector_type(4)));

__device__ __forceinline__ void gload_lds16(const float* g, float* l) {
    __builtin_amdgcn_global_load_lds(
        (const __attribute__((address_space(1))) char*)g,
        (__attribute__((address_space(3))) char*)l, 16, 0, 0);
}
__device__ __forceinline__ void gload_lds4(const float* g, float* l) {
    __builtin_amdgcn_global_load_lds(
        (const __attribute__((address_space(1))) char*)g,
        (__attribute__((address_space(3))) char*)l, 4, 0, 0);
}

// per-wave stage: 7 DMAs (6 interior rows width-16 + 1 halo width-4, 12 lanes)
__device__ __forceinline__ void stage(const float* __restrict__ xin, int ci,
                                      float (*rbuf)[256], float* hbuf,
                                      int y0, int xw, int l) {
    const float* plane = xin + (long long)ci * HWsz;
    #pragma unroll
    for (int r = 0; r < 6; ++r) {
        int yy = y0 - 1 + r;
        int yc = yy < 0 ? 0 : (yy >= IH ? IH - 1 : yy);   // clamp: pad rows
        // dest wave-uniform; HW scatters lane l -> rbuf[r][4*l]
        gload_lds16(plane + (long long)yc * IW + (xw + 4 * l), &rbuf[r][0]);
    }
    if (l < 12) {                        // 12 halo slots: lane = 2*row + side
        const int r   = l >> 1;
        const int sid = l & 1;
        int yy = y0 - 1 + r;
        int yc = yy < 0 ? 0 : (yy >= IH ? IH - 1 : yy);
        int x  = sid ? (xw + 256) : (xw - 1);
        int xc = x < 0 ? 0 : (x >= IW ? IW - 1 : x);
        // dest wave-uniform; HW scatters lane l -> hbuf[l]
        gload_lds4(plane + (long long)yc * IW + xc, &hbuf[0]);
    }
}

__device__ __forceinline__ void compute_ci(float acc[4][4][4],
                                           const float (*rbuf)[256],
                                           const float* hbuf,
                                           const float* __restrict__ wt, int ci,
                                           int y0, int l, bool xlo, bool xhi) {
    #pragma unroll
    for (int dy = 0; dy < 6; ++dy) {
        const int yy = y0 - 1 + dy;
        if (yy >= 0 && yy < IH) {                  // wave-uniform row skip
            const v4f a = *reinterpret_cast<const v4f*>(&rbuf[dy][4 * l]);
            const float L = (l == 0)  ? (xlo ? 0.f : hbuf[2 * dy])
                                      : rbuf[dy][4 * l - 1];
            const float R = (l == 63) ? (xhi ? 0.f : hbuf[2 * dy + 1])
                                      : rbuf[dy][4 * l + 4];
            float vv[6] = {L, a.x, a.y, a.z, a.w, R};
            #pragma unroll
            for (int rk = 0; rk < 3; ++rk) {
                const int o = dy - rk;             // output row offset
                if (o >= 0 && o < 4) {
                    #pragma unroll
                    for (int co = 0; co < 4; ++co) {
                        #pragma unroll
                        for (int kx = 0; kx < 3; ++kx) {
                            const float w = wt[((co * 4 + ci) * 3 + rk) * 3 + kx];
                            #pragma unroll
                            for (int p = 0; p < 4; ++p)
                                acc[o][co][p] = fmaf(w, vv[p + kx], acc[o][co][p]);
                        }
                    }
                }
            }
        }
    }
}

__global__ __launch_bounds__(256) void conv3x3_kernel(
    const float* __restrict__ xin,   // [4][4096][4096]
    const float* __restrict__ wt,    // [4][4][3][3]
    float* __restrict__ out)         // [4][4096][4096]
{
    __shared__ __align__(16) float rows[4][2][6][256];   // 49152 B (wave-private)
    __shared__ float halo[4][2][12];                     //   384 B

    // grid 4096 = 1024 row-blocks x 4 x-strips; bijective XCD swizzle
    const int bid = blockIdx.x;
    const int swz = (bid & 7) * 512 + (bid >> 3);
    const int rowblk = swz >> 2;
    const int xq     = swz & 3;
    const int y0     = rowblk << 2;               // 4 output rows
    const int X0     = xq << 10;                  // 1024-px strip
    const int t      = (int)threadIdx.x;
    const int w      = t >> 6, l = t & 63;
    const int xw     = X0 + 256 * w;              // this wave's sub-strip
    const bool xlo   = (xw == 0);                 // image left edge
    const bool xhi   = (xw + 256 == IW);          // image right edge

    float acc[4][4][4];
    #pragma unroll
    for (int o = 0; o < 4; ++o)
        #pragma unroll
        for (int co = 0; co < 4; ++co)
            #pragma unroll
            for (int p = 0; p < 4; ++p) acc[o][co][p] = 0.f;

    stage(xin, 0, rows[w][0], halo[w][0], y0, xw, l);   // prologue

    #pragma unroll 1
    for (int ci = 0; ci < 4; ++ci) {
        const int cur = ci & 1;
        if (ci < 3) {
            // my reads of buf cur^1 (from compute ci-1) must be complete
            // before the DMA overwrites it (different wait queues)
            asm volatile("s_waitcnt lgkmcnt(0)" ::: "memory");
            stage(xin, ci + 1, rows[w][cur ^ 1], halo[w][cur ^ 1], y0, xw, l);
            // wait MY oldest 7 (= ci's loads); ci+1's 7 stay in flight
            asm volatile("s_waitcnt vmcnt(7)" ::: "memory");
        } else {
            asm volatile("s_waitcnt vmcnt(0)" ::: "memory");
        }
        compute_ci(acc, rows[w][cur], halo[w][cur], wt, ci, y0, l, xlo, xhi);
    }

    const int x0g = X0 + 4 * t;
    #pragma unroll
    for (int o = 0; o < 4; ++o) {
        const long long obase = (long long)(y0 + o) * IW + x0g;
        #pragma unroll
        for (int co = 0; co < 4; ++co) {
            v4f ov;
            ov.x = acc[o][co][0]; ov.y = acc[o][co][1];
            ov.z = acc[o][co][2]; ov.w = acc[o][co][3];
            __builtin_nontemporal_store(ov,
                reinterpret_cast<v4f*>(out + co * HWsz + obase));
        }
    }
}

extern "C" void kernel_launch(void* const* d_in, const int* in_sizes, int n_in,
                              void* d_out, int out_size, void* d_ws, size_t ws_size,
                              hipStream_t stream) {
    const float* xin = (const float*)d_in[0];
    const float* wt  = (const float*)d_in[1];
    float* out       = (float*)d_out;

    dim3 grid(4096), block(256);
    hipLaunchKernelGGL(conv3x3_kernel, grid, block, 0, stream, xin, wt, out);
}

// Round 14
// 95.787 us; speedup vs baseline: 1.0956x; 1.0956x over previous
//
#include <hip/hip_runtime.h>

// Conv2d 3x3, cin=4, cout=4, pad=1, stride=1 on [4,4096,4096] fp32.
//
// Round-14: occupancy-targeted restructure of the R9 pipeline (97.9 us).
// Tile = 512px x 8 output rows per 256-thread block; thread = 4px x 4rows x
// 4cout (64 acc, unchanged). Pair 0 (waves 0-1) -> rows y0..y0+3, pair 1
// (waves 2-3) -> y0+4..y0+7. Per ci: stage 10 input rows as 20 chunk-DMAs
// (global_load_lds width=16, 256 floats each); wave w owns chunks 5w..5w+4
// -> counted s_waitcnt vmcnt(5) + s_barrier (R9 skeleton, depth-1 prefetch).
// LDS = 2 x 10 x 512 x 4B = 40960 B EXACTLY -> 4 blocks/CU = 16 waves/CU
// (vs R9's 3 blocks/12 waves). Staged bytes/output: 10/8 = 1.25x (vs 1.5x).
// Halo columns are NOT staged: their addresses are wave-uniform, so they
// come from scalar loads (readfirstlane-forced uniform -> s_load, lgkmcnt
// domain, no vmcnt pollution), cndmask'ed in for tx==0 / tx==127 lanes.

#define IW 4096
#define IH 4096
constexpr long long HWsz = (long long)IH * IW;

typedef float v4f __attribute__((ext_vector_type(4)));

__device__ __forceinline__ void gload_lds16(const float* g, float* l) {
    __builtin_amdgcn_global_load_lds(
        (const __attribute__((address_space(1))) char*)g,
        (__attribute__((address_space(3))) char*)l, 16, 0, 0);
}

// stage one ci plane: 10 rows x 2 half-rows = 20 chunks; wave w -> 5w..5w+4
__device__ __forceinline__ void stage(const float* __restrict__ xin, int ci,
                                      float (*rbuf)[512], int y0, int X0,
                                      int w, int l) {
    const float* plane = xin + (long long)ci * HWsz;
    #pragma unroll
    for (int k = 0; k < 5; ++k) {
        const int c = 5 * w + k;                 // chunk id (wave-uniform)
        const int r = c >> 1;                    // staged row 0..9
        const int h = c & 1;                     // half-strip
        int yy = y0 - 1 + r;
        int yc = yy < 0 ? 0 : (yy >= IH ? IH - 1 : yy);   // clamp: pad rows
        gload_lds16(plane + (long long)yc * IW + (X0 + 256 * h + 4 * l),
                    &rbuf[r][256 * h]);
    }
}

__device__ __forceinline__ void compute_ci(float acc[4][4][4],
                                           const float (*rbuf)[512],
                                           const float* __restrict__ xin,
                                           const float* __restrict__ wt,
                                           int ci, int y0, int X0,
                                           int p_u, int tx) {
    const float* plane = xin + (long long)ci * HWsz;
    #pragma unroll
    for (int dy = 0; dy < 6; ++dy) {
        const int r  = 4 * p_u + dy;             // staged row (wave-uniform)
        const int yy = y0 - 1 + r;               // global input row (uniform)
        if (yy >= 0 && yy < IH) {                // wave-uniform row skip
            // wave-uniform halo addresses -> scalar loads (lgkmcnt domain)
            const float hL = (X0 > 0)
                ? plane[(long long)yy * IW + X0 - 1]   : 0.f;
            const float hR = (X0 + 512 < IW)
                ? plane[(long long)yy * IW + X0 + 512] : 0.f;
            const v4f a = *reinterpret_cast<const v4f*>(&rbuf[r][4 * tx]);
            // OOB-selected LDS reads are safe; values cndmask'ed out
            const float L = (tx == 0)   ? hL : rbuf[r][4 * tx - 1];
            const float R = (tx == 127) ? hR : rbuf[r][4 * tx + 4];
            float vv[6] = {L, a.x, a.y, a.z, a.w, R};
            #pragma unroll
            for (int rk = 0; rk < 3; ++rk) {
                const int o = dy - rk;           // output row offset in pair
                if (o >= 0 && o < 4) {
                    #pragma unroll
                    for (int co = 0; co < 4; ++co) {
                        #pragma unroll
                        for (int kx = 0; kx < 3; ++kx) {
                            const float w = wt[((co * 4 + ci) * 3 + rk) * 3 + kx];
                            #pragma unroll
                            for (int p = 0; p < 4; ++p)
                                acc[o][co][p] = fmaf(w, vv[p + kx], acc[o][co][p]);
                        }
                    }
                }
            }
        }
    }
}

__global__ __launch_bounds__(256) void conv3x3_kernel(
    const float* __restrict__ xin,   // [4][4096][4096]
    const float* __restrict__ wt,    // [4][4][3][3]
    float* __restrict__ out)         // [4][4096][4096]
{
    __shared__ __align__(16) float rows[2][10][512];   // 40960 B exactly

    // grid 4096 = 512 row-blocks x 8 x-strips; bijective XCD swizzle:
    // XCD x gets swz [x*512,(x+1)*512) -> rowblk band of 64 (512 rows)
    const int bid = blockIdx.x;
    const int swz = (bid & 7) * 512 + (bid >> 3);
    const int rowblk = swz >> 3;                  // 0..511
    const int xs     = swz & 7;                   // 0..7
    const int y0     = rowblk << 3;               // 8 output rows
    const int X0     = xs << 9;                   // 512-px strip
    const int t      = (int)threadIdx.x;
    const int w      = t >> 6, l = t & 63;
    const int tx     = t & 127;                   // px index within pair
    const int p_u    = __builtin_amdgcn_readfirstlane(t >> 7);  // pair 0/1

    float acc[4][4][4];                           // [orow][cout][px]
    #pragma unroll
    for (int o = 0; o < 4; ++o)
        #pragma unroll
        for (int co = 0; co < 4; ++co)
            #pragma unroll
            for (int p = 0; p < 4; ++p) acc[o][co][p] = 0.f;

    stage(xin, 0, rows[0], y0, X0, w, l);         // prologue: 5 DMAs/wave

    #pragma unroll 1
    for (int ci = 0; ci < 4; ++ci) {
        const int cur = ci & 1;
        if (ci < 3) {
            stage(xin, ci + 1, rows[cur ^ 1], y0, X0, w, l);
            // wait MY oldest 5 (= ci's chunks); ci+1's 5 stay in flight;
            // barrier publishes all waves' phase-ci chunks
            asm volatile("s_waitcnt vmcnt(5)\n\ts_barrier" ::: "memory");
        } else {
            asm volatile("s_waitcnt vmcnt(0)\n\ts_barrier" ::: "memory");
        }
        compute_ci(acc, rows[cur], xin, wt, ci, y0, X0, p_u, tx);
        if (ci < 3)
            asm volatile("s_barrier" ::: "memory");   // readers done before
                                                      // next stage overwrites
    }

    const int x0g = X0 + 4 * tx;
    #pragma unroll
    for (int o = 0; o < 4; ++o) {
        const long long obase = (long long)(y0 + 4 * p_u + o) * IW + x0g;
        #pragma unroll
        for (int co = 0; co < 4; ++co) {
            v4f ov;
            ov.x = acc[o][co][0]; ov.y = acc[o][co][1];
            ov.z = acc[o][co][2]; ov.w = acc[o][co][3];
            __builtin_nontemporal_store(ov,
                reinterpret_cast<v4f*>(out + co * HWsz + obase));
        }
    }
}

extern "C" void kernel_launch(void* const* d_in, const int* in_sizes, int n_in,
                              void* d_out, int out_size, void* d_ws, size_t ws_size,
                              hipStream_t stream) {
    const float* xin = (const float*)d_in[0];
    const float* wt  = (const float*)d_in[1];
    float* out       = (float*)d_out;

    dim3 grid(4096), block(256);
    hipLaunchKernelGGL(conv3x3_kernel, grid, block, 0, stream, xin, wt, out);
}

// Round 15
// 95.616 us; speedup vs baseline: 1.0976x; 1.0018x over previous
//
#include <hip/hip_runtime.h>

// Conv2d 3x3, cin=4, cout=4, pad=1, stride=1 on [4,4096,4096] fp32.
//
// Round-15 = round-14 (95.8 us best: 512px x 8rows tile, 40960 B LDS ->
// 4 blocks/CU, vmcnt(5) DMA pipeline, XCD swizzle, nt stores) with ONE
// change: the FMA engine runs on PACKED FP32. Inner loops operate on
// float2 ext-vectors via __builtin_elementwise_fma, so the backend can
// select v_pk_fma_f32 (VOP3P dual-issue fp32, CDNA2+): 2304 -> 1152 FMA
// instructions per thread, ~18 pair-builds per ci. If selection fails the
// code legalizes to 2x v_fma_f32 == round-14 (bounded risk).

#define IW 4096
#define IH 4096
constexpr long long HWsz = (long long)IH * IW;

typedef float v4f __attribute__((ext_vector_type(4)));
typedef float v2f __attribute__((ext_vector_type(2)));

__device__ __forceinline__ void gload_lds16(const float* g, float* l) {
    __builtin_amdgcn_global_load_lds(
        (const __attribute__((address_space(1))) char*)g,
        (__attribute__((address_space(3))) char*)l, 16, 0, 0);
}

// stage one ci plane: 10 rows x 2 half-rows = 20 chunks; wave w -> 5w..5w+4
__device__ __forceinline__ void stage(const float* __restrict__ xin, int ci,
                                      float (*rbuf)[512], int y0, int X0,
                                      int w, int l) {
    const float* plane = xin + (long long)ci * HWsz;
    #pragma unroll
    for (int k = 0; k < 5; ++k) {
        const int c = 5 * w + k;                 // chunk id (wave-uniform)
        const int r = c >> 1;                    // staged row 0..9
        const int h = c & 1;                     // half-strip
        int yy = y0 - 1 + r;
        int yc = yy < 0 ? 0 : (yy >= IH ? IH - 1 : yy);   // clamp: pad rows
        gload_lds16(plane + (long long)yc * IW + (X0 + 256 * h + 4 * l),
                    &rbuf[r][256 * h]);
    }
}

__device__ __forceinline__ void compute_ci(v2f acc[4][4][2],
                                           const float (*rbuf)[512],
                                           const float* __restrict__ xin,
                                           const float* __restrict__ wt,
                                           int ci, int y0, int X0,
                                           int p_u, int tx) {
    const float* plane = xin + (long long)ci * HWsz;
    #pragma unroll
    for (int dy = 0; dy < 6; ++dy) {
        const int r  = 4 * p_u + dy;             // staged row (wave-uniform)
        const int yy = y0 - 1 + r;               // global input row (uniform)
        if (yy >= 0 && yy < IH) {                // wave-uniform row skip
            // wave-uniform halo addresses -> scalar loads
            const float hL = (X0 > 0)
                ? plane[(long long)yy * IW + X0 - 1]   : 0.f;
            const float hR = (X0 + 512 < IW)
                ? plane[(long long)yy * IW + X0 + 512] : 0.f;
            const v4f a = *reinterpret_cast<const v4f*>(&rbuf[r][4 * tx]);
            const float L = (tx == 0)   ? hL : rbuf[r][4 * tx - 1];
            const float R = (tx == 127) ? hR : rbuf[r][4 * tx + 4];
            const float vv[6] = {L, a.x, a.y, a.z, a.w, R};
            #pragma unroll
            for (int kx = 0; kx < 3; ++kx) {
                // shared pair operands for all (o, co) at this (dy, kx)
                const v2f pa = {vv[kx],     vv[kx + 1]};
                const v2f pb = {vv[kx + 2], vv[kx + 3]};
                #pragma unroll
                for (int rk = 0; rk < 3; ++rk) {
                    const int o = dy - rk;       // output row offset in pair
                    if (o >= 0 && o < 4) {
                        #pragma unroll
                        for (int co = 0; co < 4; ++co) {
                            const float w =
                                wt[((co * 4 + ci) * 3 + rk) * 3 + kx];
                            const v2f wv = {w, w};
                            acc[o][co][0] =
                                __builtin_elementwise_fma(pa, wv, acc[o][co][0]);
                            acc[o][co][1] =
                                __builtin_elementwise_fma(pb, wv, acc[o][co][1]);
                        }
                    }
                }
            }
        }
    }
}

__global__ __launch_bounds__(256) void conv3x3_kernel(
    const float* __restrict__ xin,   // [4][4096][4096]
    const float* __restrict__ wt,    // [4][4][3][3]
    float* __restrict__ out)         // [4][4096][4096]
{
    __shared__ __align__(16) float rows[2][10][512];   // 40960 B exactly

    // grid 4096 = 512 row-blocks x 8 x-strips; bijective XCD swizzle
    const int bid = blockIdx.x;
    const int swz = (bid & 7) * 512 + (bid >> 3);
    const int rowblk = swz >> 3;                  // 0..511
    const int xs     = swz & 7;                   // 0..7
    const int y0     = rowblk << 3;               // 8 output rows
    const int X0     = xs << 9;                   // 512-px strip
    const int t      = (int)threadIdx.x;
    const int w      = t >> 6, l = t & 63;
    const int tx     = t & 127;                   // px index within pair
    const int p_u    = __builtin_amdgcn_readfirstlane(t >> 7);  // pair 0/1

    v2f acc[4][4][2];                             // [orow][cout][pxpair]
    #pragma unroll
    for (int o = 0; o < 4; ++o)
        #pragma unroll
        for (int co = 0; co < 4; ++co) {
            acc[o][co][0] = (v2f){0.f, 0.f};
            acc[o][co][1] = (v2f){0.f, 0.f};
        }

    stage(xin, 0, rows[0], y0, X0, w, l);         // prologue: 5 DMAs/wave

    #pragma unroll 1
    for (int ci = 0; ci < 4; ++ci) {
        const int cur = ci & 1;
        if (ci < 3) {
            stage(xin, ci + 1, rows[cur ^ 1], y0, X0, w, l);
            // wait MY oldest 5 (= ci's chunks); ci+1's 5 stay in flight
            asm volatile("s_waitcnt vmcnt(5)\n\ts_barrier" ::: "memory");
        } else {
            asm volatile("s_waitcnt vmcnt(0)\n\ts_barrier" ::: "memory");
        }
        compute_ci(acc, rows[cur], xin, wt, ci, y0, X0, p_u, tx);
        if (ci < 3)
            asm volatile("s_barrier" ::: "memory");   // readers done before
                                                      // next stage overwrites
    }

    const int x0g = X0 + 4 * tx;
    #pragma unroll
    for (int o = 0; o < 4; ++o) {
        const long long obase = (long long)(y0 + 4 * p_u + o) * IW + x0g;
        #pragma unroll
        for (int co = 0; co < 4; ++co) {
            v4f ov;
            ov.x = acc[o][co][0].x; ov.y = acc[o][co][0].y;
            ov.z = acc[o][co][1].x; ov.w = acc[o][co][1].y;
            __builtin_nontemporal_store(ov,
                reinterpret_cast<v4f*>(out + co * HWsz + obase));
        }
    }
}

extern "C" void kernel_launch(void* const* d_in, const int* in_sizes, int n_in,
                              void* d_out, int out_size, void* d_ws, size_t ws_size,
                              hipStream_t stream) {
    const float* xin = (const float*)d_in[0];
    const float* wt  = (const float*)d_in[1];
    float* out       = (float*)d_out;

    dim3 grid(4096), block(256);
    hipLaunchKernelGGL(conv3x3_kernel, grid, block, 0, stream, xin, wt, out);
}